// Round 5
// baseline (247.876 us; speedup 1.0000x reference)
//
#include <hip/hip_runtime.h>

#define S 4096
#define DM 1024
#define NH 16
#define HD 64

typedef __attribute__((ext_vector_type(8))) short bf8;
typedef __attribute__((ext_vector_type(4))) float f4;
typedef __attribute__((ext_vector_type(4))) short s4;

#define MFMA __builtin_amdgcn_mfma_f32_16x16x32_bf16

// softmax scale folded into Q, in base-2 domain: 1/sqrt(64) * log2(e)
#define QSCALE 0.18033688011112042f

static __device__ __forceinline__ unsigned short f2b(float f) {
  unsigned int u = __builtin_bit_cast(unsigned int, f);
  u += 0x7fffu + ((u >> 16) & 1u);   // RNE
  return (unsigned short)(u >> 16);
}

// async global->LDS, 16B per lane. LDS dest must be WAVE-UNIFORM base;
// HW scatters lane i to base + i*16.
static __device__ __forceinline__ void gld_lds(const unsigned short* g, unsigned short* l) {
  __builtin_amdgcn_global_load_lds(
      (const __attribute__((address_space(1))) unsigned int*)g,
      (__attribute__((address_space(3))) unsigned int*)l, 16, 0, 0);
}

// ---------------- cast fp32 -> bf16 (contiguous) ----------------
__global__ void cast_bf16(const float* __restrict__ in, unsigned short* __restrict__ out, int n) {
  int i = (blockIdx.x * 256 + threadIdx.x) * 4;
  if (i >= n) return;
  float4 v = *(const float4*)(in + i);
  s4 o;
  o.x = (short)f2b(v.x); o.y = (short)f2b(v.y);
  o.z = (short)f2b(v.z); o.w = (short)f2b(v.w);
  *(s4*)(out + i) = o;
}

// ------------- transpose + cast: in[R][C] fp32 -> out[C][R] bf16 -------------
__global__ void transpose_cast(const float* __restrict__ in, unsigned short* __restrict__ out,
                               int R, int C) {
  __shared__ float tile[64][65];
  int tc = blockIdx.x, tr = blockIdx.y;
  int t = threadIdx.x;
  int c = t & 63, rbase = (t >> 6) * 16;
#pragma unroll
  for (int i = 0; i < 16; i++) {
    int r = rbase + i;
    tile[r][c] = in[(tr * 64 + r) * C + tc * 64 + c];
  }
  __syncthreads();
#pragma unroll
  for (int i = 0; i < 16; i++) {
    int cc = rbase + i;
    out[(tc * 64 + cc) * R + tr * 64 + c] = f2b(tile[c][cc]);
  }
}

// =================================================================
// m97-style 128x128 GEMM core, BK=32, 256 threads (4 waves, 2x2 of 64x64).
// =================================================================

// ------------- QKV GEMM + scatter epilogue -------------
__global__ void __launch_bounds__(256, 2) gemm_qkv(const unsigned short* __restrict__ A,
                                                   const unsigned short* __restrict__ Bt,
                                                   const float* __restrict__ bias,
                                                   unsigned short* __restrict__ Qo,
                                                   unsigned short* __restrict__ Ko,
                                                   unsigned short* __restrict__ Vt) {
  __shared__ unsigned short lA[128 * 32];
  __shared__ unsigned short lB[128 * 32];
  int bid = blockIdx.x;
  int nb = bid % 24, mb = bid / 24;
  int m0 = mb * 128, n0 = nb * 128;
  int t = threadIdx.x, w = t >> 6, lane = t & 63;
  int col = lane & 15, quad = lane >> 4;
  int wm = (w >> 1) * 64, wn = (w & 1) * 64;

  int srow = lane >> 2;          // 0..15 within a 16-row staging group
  int sphys = lane & 3;

  f4 acc[4][4];
#pragma unroll
  for (int x = 0; x < 4; x++)
#pragma unroll
    for (int y = 0; y < 4; y++) acc[x][y] = (f4){0.f, 0.f, 0.f, 0.f};

  for (int k0 = 0; k0 < DM; k0 += 32) {
    __syncthreads();   // WAR: prev-step consumers done
#pragma unroll
    for (int p = 0; p < 2; p++) {
      int j = 2 * w + p;
      int row = j * 16 + srow;                 // 0..127
      int lch = sphys ^ ((srow >> 1) & 3);     // logical 16B chunk to fetch
      gld_lds(A + (size_t)(m0 + row) * DM + k0 + lch * 8, lA + j * 512);
      gld_lds(Bt + (size_t)(n0 + row) * DM + k0 + lch * 8, lB + j * 512);
    }
    __syncthreads();   // staged data visible

    bf8 af[4], bfr[4];
#pragma unroll
    for (int x = 0; x < 4; x++) {
      int rA = wm + x * 16 + col;
      af[x] = *(const bf8*)(lA + rA * 32 + (quad ^ ((col >> 1) & 3)) * 8);
      int rB = wn + x * 16 + col;
      bfr[x] = *(const bf8*)(lB + rB * 32 + (quad ^ ((col >> 1) & 3)) * 8);
    }
#pragma unroll
    for (int x = 0; x < 4; x++)
#pragma unroll
      for (int y = 0; y < 4; y++)
        acc[x][y] = MFMA(af[x], bfr[y], acc[x][y], 0, 0, 0);
  }

  // epilogue: scatter to Q (scaled), K, Vt
#pragma unroll
  for (int x = 0; x < 4; x++) {
    int s0r = m0 + wm + x * 16 + quad * 4;
#pragma unroll
    for (int y = 0; y < 4; y++) {
      f4 a = acc[x][y];
      int n = n0 + wn + y * 16 + col;
      float bv = bias[n];
      if (n < 2048) {
        unsigned short* dst = (n < 1024) ? Qo : Ko;
        float sc = (n < 1024) ? QSCALE : 1.0f;
        int nn = n & 1023;
        int hh = nn >> 6, d = nn & 63;
        unsigned short* pp = dst + ((size_t)hh * S + s0r) * HD + d;
#pragma unroll
        for (int r = 0; r < 4; r++) pp[r * HD] = f2b((a[r] + bv) * sc);
      } else {
        int nn = n - 2048;
        int hh = nn >> 6, d = nn & 63;
        s4 pk;
        pk.x = (short)f2b(a[0] + bv);
        pk.y = (short)f2b(a[1] + bv);
        pk.z = (short)f2b(a[2] + bv);
        pk.w = (short)f2b(a[3] + bv);
        *(s4*)(Vt + ((size_t)hh * HD + d) * S + s0r) = pk;
      }
    }
  }
}

// ------------- Out GEMM: ctx x woutT + bias -> fp32 -------------
__global__ void __launch_bounds__(256, 2) gemm_out(const unsigned short* __restrict__ A,
                                                   const unsigned short* __restrict__ Bt,
                                                   const float* __restrict__ bias,
                                                   float* __restrict__ out) {
  __shared__ unsigned short lA[128 * 32];
  __shared__ unsigned short lB[128 * 32];
  int bid = blockIdx.x;
  int nb = bid % 8, mb = bid / 8;
  int m0 = mb * 128, n0 = nb * 128;
  int t = threadIdx.x, w = t >> 6, lane = t & 63;
  int col = lane & 15, quad = lane >> 4;
  int wm = (w >> 1) * 64, wn = (w & 1) * 64;

  int srow = lane >> 2;
  int sphys = lane & 3;

  f4 acc[4][4];
#pragma unroll
  for (int x = 0; x < 4; x++)
#pragma unroll
    for (int y = 0; y < 4; y++) acc[x][y] = (f4){0.f, 0.f, 0.f, 0.f};

  for (int k0 = 0; k0 < DM; k0 += 32) {
    __syncthreads();
#pragma unroll
    for (int p = 0; p < 2; p++) {
      int j = 2 * w + p;
      int row = j * 16 + srow;
      int lch = sphys ^ ((srow >> 1) & 3);
      gld_lds(A + (size_t)(m0 + row) * DM + k0 + lch * 8, lA + j * 512);
      gld_lds(Bt + (size_t)(n0 + row) * DM + k0 + lch * 8, lB + j * 512);
    }
    __syncthreads();

    bf8 af[4], bfr[4];
#pragma unroll
    for (int x = 0; x < 4; x++) {
      int rA = wm + x * 16 + col;
      af[x] = *(const bf8*)(lA + rA * 32 + (quad ^ ((col >> 1) & 3)) * 8);
      int rB = wn + x * 16 + col;
      bfr[x] = *(const bf8*)(lB + rB * 32 + (quad ^ ((col >> 1) & 3)) * 8);
    }
#pragma unroll
    for (int x = 0; x < 4; x++)
#pragma unroll
      for (int y = 0; y < 4; y++)
        acc[x][y] = MFMA(af[x], bfr[y], acc[x][y], 0, 0, 0);
  }

#pragma unroll
  for (int x = 0; x < 4; x++) {
    int s0r = m0 + wm + x * 16 + quad * 4;
#pragma unroll
    for (int y = 0; y < 4; y++) {
      f4 a = acc[x][y];
      int n = n0 + wn + y * 16 + col;
      float bv = bias[n];
#pragma unroll
      for (int r = 0; r < 4; r++) out[(size_t)(s0r + r) * DM + n] = a[r] + bv;
    }
  }
}

// =================================================================
// Flash attention v3: fixed-max softmax, 32 q-rows/wave (2 q-tiles,
// K/V fragment reuse x2), K staged in LDS, V-frags direct from global
// (L2), uniform 16-step kv-chunks with fp32 atomic combine.
// Groups g=0..31 (128 q-rows each) need 2g+2 kv-steps:
//   g<8: single chunk -> normalize in-reg, write ctx bf16 directly.
//   g>=8: ceil((2g+2)/16) chunks -> atomicAdd fp32 partial O + l.
// Slot schedule (per head, 80 slots): 0..47 full 16-step chunks
// (= exactly residency, uniform), 48..79 tails (desc length backfill).
// =================================================================
__global__ void __launch_bounds__(256, 3) attn(const unsigned short* __restrict__ Q,
                                               const unsigned short* __restrict__ K,
                                               const unsigned short* __restrict__ Vt,
                                               unsigned short* __restrict__ Ctx,
                                               float* __restrict__ part,   // [3072][1024] rows 1024+
                                               float* __restrict__ lg) {   // [16][3072]
  __shared__ unsigned short kbuf[64 * 64];        // [kv][d], swizzled chunks
  __shared__ unsigned short pbuf[4 * 2 * 16 * 72];

  int bid = blockIdx.x;
  int h = bid & 15, slot = bid >> 4;
  int g, c, nst;
  if (slot < 24)      { g = 24 + slot / 3;        c = slot % 3;        nst = 16; }
  else if (slot < 40) { g = 16 + (slot - 24) / 2; c = (slot - 24) & 1; nst = 16; }
  else if (slot < 48) { g = 8 + (slot - 40);      c = 0;               nst = 16; }
  else {
    int t2 = slot - 48;
    int mm = 7 - (t2 >> 2);
    g = mm + 8 * (t2 & 3);
    c = g >> 3;
    nst = (2 * g + 2) - 16 * c;
  }
  bool single = (g < 8);

  int t = threadIdx.x, w = t >> 6, lane = t & 63;
  int col = lane & 15, quad = lane >> 4;
  int q0a = g * 128 + w * 32;
  int q0b = q0a + 16;

  const unsigned short* Qh = Q + (size_t)h * S * HD;
  const unsigned short* Kh = K + (size_t)h * S * HD;
  const unsigned short* Vh = Vt + (size_t)h * HD * S;
  unsigned short* pla = pbuf + w * (2 * 16 * 72);
  unsigned short* plb = pla + 16 * 72;

  // Q^T B-fragments for both q-tiles
  bf8 qa0 = *(const bf8*)(Qh + (q0a + col) * HD + quad * 8);
  bf8 qa1 = *(const bf8*)(Qh + (q0a + col) * HD + 32 + quad * 8);
  bf8 qb0 = *(const bf8*)(Qh + (q0b + col) * HD + quad * 8);
  bf8 qb1 = *(const bf8*)(Qh + (q0b + col) * HD + 32 + quad * 8);

  f4 oa[4], ob[4];
#pragma unroll
  for (int dt = 0; dt < 4; dt++) { oa[dt] = (f4){0.f,0.f,0.f,0.f}; ob[dt] = (f4){0.f,0.f,0.f,0.f}; }
  float lsa = 0.f, lsb = 0.f;

  int srow = lane >> 3, sphys = lane & 7;
  int sw = col & 7;

  for (int s_ = 0; s_ < nst; s_++) {
    int kv0 = (c * 16 + s_) * 64;
    __syncthreads();             // WAR: prev-step kbuf consumers done
#pragma unroll
    for (int p = 0; p < 2; p++) {
      int j = 2 * w + p;
      int row = j * 8 + srow;                  // 0..63
      int lch = sphys ^ (row & 7);
      gld_lds(Kh + (size_t)(kv0 + row) * HD + lch * 8, kbuf + j * 512);
    }
    __syncthreads();             // staged data visible

    // V B-fragments straight from global (L2-resident tiles)
    bf8 vf0[4], vf1[4];
#pragma unroll
    for (int dt = 0; dt < 4; dt++) {
      const unsigned short* vp = Vh + (size_t)(dt * 16 + col) * S + kv0 + quad * 8;
      vf0[dt] = *(const bf8*)(vp);
      vf1[dt] = *(const bf8*)(vp + 32);
    }

    // K A-fragments (shared by both q-tiles)
    bf8 kf0[4], kf1[4];
#pragma unroll
    for (int tt = 0; tt < 4; tt++) {
      int kr = tt * 16 + col;
      kf0[tt] = *(const bf8*)(kbuf + kr * 64 + (quad ^ sw) * 8);
      kf1[tt] = *(const bf8*)(kbuf + kr * 64 + ((quad + 4) ^ sw) * 8);
    }

    // ---- scores S^T[kv][q] for both q-tiles ----
    f4 sta[4], stb[4];
#pragma unroll
    for (int tt = 0; tt < 4; tt++) {
      f4 z = {0.f, 0.f, 0.f, 0.f};
      z = MFMA(kf0[tt], qa0, z, 0, 0, 0);
      z = MFMA(kf1[tt], qa1, z, 0, 0, 0);
      sta[tt] = z;
      f4 y = {0.f, 0.f, 0.f, 0.f};
      y = MFMA(kf0[tt], qb0, y, 0, 0, 0);
      y = MFMA(kf1[tt], qb1, y, 0, 0, 0);
      stb[tt] = y;
    }

    if (kv0 + 63 > q0a) {
      int q = q0a + col;
#pragma unroll
      for (int tt = 0; tt < 4; tt++)
#pragma unroll
        for (int rr = 0; rr < 4; rr++) {
          int kv = kv0 + tt * 16 + quad * 4 + rr;
          sta[tt][rr] = (kv <= q) ? sta[tt][rr] : -1e30f;
        }
    }
    if (kv0 + 63 > q0b) {
      int q = q0b + col;
#pragma unroll
      for (int tt = 0; tt < 4; tt++)
#pragma unroll
        for (int rr = 0; rr < 4; rr++) {
          int kv = kv0 + tt * 16 + quad * 4 + rr;
          stb[tt][rr] = (kv <= q) ? stb[tt][rr] : -1e30f;
        }
    }

    // ---- fixed-max softmax: p = exp2(st); per-lane l accumulate ----
#pragma unroll
    for (int tt = 0; tt < 4; tt++) {
      float a0 = __builtin_amdgcn_exp2f(sta[tt][0]);
      float a1 = __builtin_amdgcn_exp2f(sta[tt][1]);
      float a2 = __builtin_amdgcn_exp2f(sta[tt][2]);
      float a3 = __builtin_amdgcn_exp2f(sta[tt][3]);
      lsa += (a0 + a1) + (a2 + a3);
      s4 pk;
      pk.x = (short)f2b(a0); pk.y = (short)f2b(a1);
      pk.z = (short)f2b(a2); pk.w = (short)f2b(a3);
      *(s4*)((char*)pla + col * 144 + tt * 32 + quad * 8) = pk;

      float b0 = __builtin_amdgcn_exp2f(stb[tt][0]);
      float b1 = __builtin_amdgcn_exp2f(stb[tt][1]);
      float b2 = __builtin_amdgcn_exp2f(stb[tt][2]);
      float b3 = __builtin_amdgcn_exp2f(stb[tt][3]);
      lsb += (b0 + b1) + (b2 + b3);
      s4 qk;
      qk.x = (short)f2b(b0); qk.y = (short)f2b(b1);
      qk.z = (short)f2b(b2); qk.w = (short)f2b(b3);
      *(s4*)((char*)plb + col * 144 + tt * 32 + quad * 8) = qk;
    }

    // P A-fragments (own-wave LDS; same-wave RAW is in-order at the DS unit)
    bf8 pa0 = *(const bf8*)(pla + col * 72 + quad * 8);
    bf8 pa1 = *(const bf8*)(pla + col * 72 + 32 + quad * 8);
    bf8 pb0 = *(const bf8*)(plb + col * 72 + quad * 8);
    bf8 pb1 = *(const bf8*)(plb + col * 72 + 32 + quad * 8);

#pragma unroll
    for (int dt = 0; dt < 4; dt++) {
      oa[dt] = MFMA(pa0, vf0[dt], oa[dt], 0, 0, 0);
      oa[dt] = MFMA(pa1, vf1[dt], oa[dt], 0, 0, 0);
      ob[dt] = MFMA(pb0, vf0[dt], ob[dt], 0, 0, 0);
      ob[dt] = MFMA(pb1, vf1[dt], ob[dt], 0, 0, 0);
    }
  }

  // ---- epilogue ----
  lsa += __shfl_xor(lsa, 16); lsa += __shfl_xor(lsa, 32);
  lsb += __shfl_xor(lsb, 16); lsb += __shfl_xor(lsb, 32);

  if (single) {
    float ia = 1.0f / lsa, ib = 1.0f / lsb;
    float ira[4], irb[4];
#pragma unroll
    for (int r = 0; r < 4; r++) { ira[r] = __shfl(ia, quad * 4 + r); irb[r] = __shfl(ib, quad * 4 + r); }
#pragma unroll
    for (int dt = 0; dt < 4; dt++)
#pragma unroll
      for (int r = 0; r < 4; r++) {
        Ctx[(size_t)(q0a + quad * 4 + r) * DM + h * HD + dt * 16 + col] = f2b(oa[dt][r] * ira[r]);
        Ctx[(size_t)(q0b + quad * 4 + r) * DM + h * HD + dt * 16 + col] = f2b(ob[dt][r] * irb[r]);
      }
  } else {
    if (quad == 0) {
      atomicAdd(&lg[h * 3072 + (q0a + col - 1024)], lsa);
      atomicAdd(&lg[h * 3072 + (q0b + col - 1024)], lsb);
    }
#pragma unroll
    for (int dt = 0; dt < 4; dt++)
#pragma unroll
      for (int r = 0; r < 4; r++) {
        atomicAdd(&part[(size_t)(q0a + quad * 4 + r - 1024) * DM + h * HD + dt * 16 + col], oa[dt][r]);
        atomicAdd(&part[(size_t)(q0b + quad * 4 + r - 1024) * DM + h * HD + dt * 16 + col], ob[dt][r]);
      }
  }
}

// ------------- combine fp32 partials -> normalized ctx rows 1024+ -------------
__global__ void combine(unsigned short* __restrict__ Ctx,
                        const float* __restrict__ part,
                        const float* __restrict__ lg) {
  int idx = blockIdx.x * 1024 + threadIdx.x * 4;   // over 3072*1024
  int r = idx >> 10;            // row - 1024
  int cc = idx & 1023, h = cc >> 6;
  float4 v = *(const float4*)(part + idx);
  float inv = 1.0f / lg[h * 3072 + r];
  s4 o;
  o.x = (short)f2b(v.x * inv); o.y = (short)f2b(v.y * inv);
  o.z = (short)f2b(v.z * inv); o.w = (short)f2b(v.w * inv);
  *(s4*)(Ctx + (size_t)(r + 1024) * DM + cc) = o;
}

extern "C" void kernel_launch(void* const* d_in, const int* in_sizes, int n_in,
                              void* d_out, int out_size, void* d_ws, size_t ws_size,
                              hipStream_t stream) {
  const float* x     = (const float*)d_in[0];
  const float* w_qkv = (const float*)d_in[1];
  const float* b_qkv = (const float*)d_in[2];
  const float* w_out = (const float*)d_in[3];
  const float* b_out = (const float*)d_in[4];
  float* out = (float*)d_out;

  char* ws = (char*)d_ws;
  unsigned short* xb    = (unsigned short*)(ws);                        //  8 MB (dead after gemm_qkv)
  unsigned short* wqkvT = (unsigned short*)(ws + (size_t)8  * 1048576); //  6 MB (dead after gemm_qkv)
  unsigned short* woutT = (unsigned short*)(ws + (size_t)14 * 1048576); //  2 MB (live till gemm_out)
  unsigned short* Qb    = (unsigned short*)(ws + (size_t)16 * 1048576); //  8 MB
  unsigned short* Kb    = (unsigned short*)(ws + (size_t)24 * 1048576); //  8 MB
  unsigned short* Vtb   = (unsigned short*)(ws + (size_t)32 * 1048576); //  8 MB
  unsigned short* ctx   = (unsigned short*)(ws + (size_t)40 * 1048576); //  8 MB

  // dead-region reuse after gemm_qkv: fp32 partial O (rows 1024+) + l
  float* part = (float*)ws;                                             // 12 MB
  float* lg   = (float*)(ws + (size_t)12 * 1048576);                    // 192 KB

  cast_bf16<<<4096, 256, 0, stream>>>(x, xb, S * DM);
  transpose_cast<<<dim3(3 * DM / 64, DM / 64), 256, 0, stream>>>(w_qkv, wqkvT, DM, 3 * DM);
  transpose_cast<<<dim3(DM / 64, DM / 64), 256, 0, stream>>>(w_out, woutT, DM, DM);
  gemm_qkv<<<32 * 24, 256, 0, stream>>>(xb, wqkvT, b_qkv, Qb, Kb, Vtb);
  hipMemsetAsync(ws, 0, (size_t)12 * 1048576 + 196608, stream);
  attn<<<NH * 80, 256, 0, stream>>>(Qb, Kb, Vtb, ctx, part, lg);
  combine<<<3072, 256, 0, stream>>>(ctx, part, lg);
  gemm_out<<<32 * 8, 256, 0, stream>>>(ctx, woutT, b_out, out);
}

// Round 6
// 235.444 us; speedup vs baseline: 1.0528x; 1.0528x over previous
//
#include <hip/hip_runtime.h>

#define S 4096
#define DM 1024
#define NH 16
#define HD 64

typedef __attribute__((ext_vector_type(8))) short bf8;
typedef __attribute__((ext_vector_type(4))) float f4;
typedef __attribute__((ext_vector_type(4))) short s4;

#define MFMA __builtin_amdgcn_mfma_f32_16x16x32_bf16

// softmax scale folded into Q, in base-2 domain: 1/sqrt(64) * log2(e)
#define QSCALE 0.18033688011112042f

static __device__ __forceinline__ unsigned short f2b(float f) {
  unsigned int u = __builtin_bit_cast(unsigned int, f);
  u += 0x7fffu + ((u >> 16) & 1u);   // RNE
  return (unsigned short)(u >> 16);
}
static __device__ __forceinline__ float b2f(unsigned short u) {
  return __builtin_bit_cast(float, (unsigned int)u << 16);
}

// async global->LDS, 16B per lane. LDS dest must be WAVE-UNIFORM base;
// HW scatters lane i to base + i*16.
static __device__ __forceinline__ void gld_lds(const unsigned short* g, unsigned short* l) {
  __builtin_amdgcn_global_load_lds(
      (const __attribute__((address_space(1))) unsigned int*)g,
      (__attribute__((address_space(3))) unsigned int*)l, 16, 0, 0);
}

// ---------------- cast fp32 -> bf16 (contiguous) ----------------
__global__ void cast_bf16(const float* __restrict__ in, unsigned short* __restrict__ out, int n) {
  int i = (blockIdx.x * 256 + threadIdx.x) * 4;
  if (i >= n) return;
  float4 v = *(const float4*)(in + i);
  s4 o;
  o.x = (short)f2b(v.x); o.y = (short)f2b(v.y);
  o.z = (short)f2b(v.z); o.w = (short)f2b(v.w);
  *(s4*)(out + i) = o;
}

// ------------- transpose + cast: in[R][C] fp32 -> out[C][R] bf16 -------------
__global__ void transpose_cast(const float* __restrict__ in, unsigned short* __restrict__ out,
                               int R, int C) {
  __shared__ float tile[64][65];
  int tc = blockIdx.x, tr = blockIdx.y;
  int t = threadIdx.x;
  int c = t & 63, rbase = (t >> 6) * 16;
#pragma unroll
  for (int i = 0; i < 16; i++) {
    int r = rbase + i;
    tile[r][c] = in[(tr * 64 + r) * C + tc * 64 + c];
  }
  __syncthreads();
#pragma unroll
  for (int i = 0; i < 16; i++) {
    int cc = rbase + i;
    out[(tc * 64 + cc) * R + tr * 64 + c] = f2b(tile[c][cc]);
  }
}

// =================================================================
// m97-style 128x128 GEMM core, BK=32, 256 threads (4 waves, 2x2 of 64x64).
// =================================================================

// ------------- QKV GEMM + scatter epilogue -------------
__global__ void __launch_bounds__(256, 2) gemm_qkv(const unsigned short* __restrict__ A,
                                                   const unsigned short* __restrict__ Bt,
                                                   const float* __restrict__ bias,
                                                   unsigned short* __restrict__ Qo,
                                                   unsigned short* __restrict__ Ko,
                                                   unsigned short* __restrict__ Vt) {
  __shared__ unsigned short lA[128 * 32];
  __shared__ unsigned short lB[128 * 32];
  int bid = blockIdx.x;
  int nb = bid % 24, mb = bid / 24;
  int m0 = mb * 128, n0 = nb * 128;
  int t = threadIdx.x, w = t >> 6, lane = t & 63;
  int col = lane & 15, quad = lane >> 4;
  int wm = (w >> 1) * 64, wn = (w & 1) * 64;

  int srow = lane >> 2;          // 0..15 within a 16-row staging group
  int sphys = lane & 3;

  f4 acc[4][4];
#pragma unroll
  for (int x = 0; x < 4; x++)
#pragma unroll
    for (int y = 0; y < 4; y++) acc[x][y] = (f4){0.f, 0.f, 0.f, 0.f};

  for (int k0 = 0; k0 < DM; k0 += 32) {
    __syncthreads();   // WAR: prev-step consumers done
#pragma unroll
    for (int p = 0; p < 2; p++) {
      int j = 2 * w + p;
      int row = j * 16 + srow;                 // 0..127
      int lch = sphys ^ ((srow >> 1) & 3);     // logical 16B chunk to fetch
      gld_lds(A + (size_t)(m0 + row) * DM + k0 + lch * 8, lA + j * 512);
      gld_lds(Bt + (size_t)(n0 + row) * DM + k0 + lch * 8, lB + j * 512);
    }
    __syncthreads();   // staged data visible

    bf8 af[4], bfr[4];
#pragma unroll
    for (int x = 0; x < 4; x++) {
      int rA = wm + x * 16 + col;
      af[x] = *(const bf8*)(lA + rA * 32 + (quad ^ ((col >> 1) & 3)) * 8);
      int rB = wn + x * 16 + col;
      bfr[x] = *(const bf8*)(lB + rB * 32 + (quad ^ ((col >> 1) & 3)) * 8);
    }
#pragma unroll
    for (int x = 0; x < 4; x++)
#pragma unroll
      for (int y = 0; y < 4; y++)
        acc[x][y] = MFMA(af[x], bfr[y], acc[x][y], 0, 0, 0);
  }

  // epilogue: scatter to Q (scaled), K, Vt
#pragma unroll
  for (int x = 0; x < 4; x++) {
    int s0r = m0 + wm + x * 16 + quad * 4;
#pragma unroll
    for (int y = 0; y < 4; y++) {
      f4 a = acc[x][y];
      int n = n0 + wn + y * 16 + col;
      float bv = bias[n];
      if (n < 2048) {
        unsigned short* dst = (n < 1024) ? Qo : Ko;
        float sc = (n < 1024) ? QSCALE : 1.0f;
        int nn = n & 1023;
        int hh = nn >> 6, d = nn & 63;
        unsigned short* pp = dst + ((size_t)hh * S + s0r) * HD + d;
#pragma unroll
        for (int r = 0; r < 4; r++) pp[r * HD] = f2b((a[r] + bv) * sc);
      } else {
        int nn = n - 2048;
        int hh = nn >> 6, d = nn & 63;
        s4 pk;
        pk.x = (short)f2b(a[0] + bv);
        pk.y = (short)f2b(a[1] + bv);
        pk.z = (short)f2b(a[2] + bv);
        pk.w = (short)f2b(a[3] + bv);
        *(s4*)(Vt + ((size_t)hh * HD + d) * S + s0r) = pk;
      }
    }
  }
}

// ------------- Out GEMM: ctx x woutT + bias -> fp32 -------------
__global__ void __launch_bounds__(256, 2) gemm_out(const unsigned short* __restrict__ A,
                                                   const unsigned short* __restrict__ Bt,
                                                   const float* __restrict__ bias,
                                                   float* __restrict__ out) {
  __shared__ unsigned short lA[128 * 32];
  __shared__ unsigned short lB[128 * 32];
  int bid = blockIdx.x;
  int nb = bid % 8, mb = bid / 8;
  int m0 = mb * 128, n0 = nb * 128;
  int t = threadIdx.x, w = t >> 6, lane = t & 63;
  int col = lane & 15, quad = lane >> 4;
  int wm = (w >> 1) * 64, wn = (w & 1) * 64;

  int srow = lane >> 2;
  int sphys = lane & 3;

  f4 acc[4][4];
#pragma unroll
  for (int x = 0; x < 4; x++)
#pragma unroll
    for (int y = 0; y < 4; y++) acc[x][y] = (f4){0.f, 0.f, 0.f, 0.f};

  for (int k0 = 0; k0 < DM; k0 += 32) {
    __syncthreads();
#pragma unroll
    for (int p = 0; p < 2; p++) {
      int j = 2 * w + p;
      int row = j * 16 + srow;
      int lch = sphys ^ ((srow >> 1) & 3);
      gld_lds(A + (size_t)(m0 + row) * DM + k0 + lch * 8, lA + j * 512);
      gld_lds(Bt + (size_t)(n0 + row) * DM + k0 + lch * 8, lB + j * 512);
    }
    __syncthreads();

    bf8 af[4], bfr[4];
#pragma unroll
    for (int x = 0; x < 4; x++) {
      int rA = wm + x * 16 + col;
      af[x] = *(const bf8*)(lA + rA * 32 + (quad ^ ((col >> 1) & 3)) * 8);
      int rB = wn + x * 16 + col;
      bfr[x] = *(const bf8*)(lB + rB * 32 + (quad ^ ((col >> 1) & 3)) * 8);
    }
#pragma unroll
    for (int x = 0; x < 4; x++)
#pragma unroll
      for (int y = 0; y < 4; y++)
        acc[x][y] = MFMA(af[x], bfr[y], acc[x][y], 0, 0, 0);
  }

#pragma unroll
  for (int x = 0; x < 4; x++) {
    int s0r = m0 + wm + x * 16 + quad * 4;
#pragma unroll
    for (int y = 0; y < 4; y++) {
      f4 a = acc[x][y];
      int n = n0 + wn + y * 16 + col;
      float bv = bias[n];
#pragma unroll
      for (int r = 0; r < 4; r++) out[(size_t)(s0r + r) * DM + n] = a[r] + bv;
    }
  }
}

// =================================================================
// Flash attention v4: fixed-max softmax (m=0), 32 q-rows/wave
// (2 q-tiles, K/V fragment reuse x2), K AND V staged in LDS (R4
// dataflow), uniform 16-step kv-chunks, NO atomics:
// group g (128 q-rows) needs C_g=ceil((2g+2)/16) chunks.
//   g<8 (C=1): normalize in-reg, write ctx directly.
//   else chunk c partial (bf16, unnormalized) -> c==0: ctx rows as-is;
//        c==1: slab1 (rows-1024); c==2: slab2 (-2048); c==3: slab3 (-3072).
//   l partials -> lbase[c][h][q] (fp32). Every cell written once.
// Slot schedule per head (80): 0..47 full 16-step chunks, 48..79 tails
// in descending length (16,14,12,10 | 8,6,4,2) for backfill.
// =================================================================
__global__ void __launch_bounds__(256, 4) attn(const unsigned short* __restrict__ Q,
                                               const unsigned short* __restrict__ K,
                                               const unsigned short* __restrict__ Vt,
                                               unsigned short* __restrict__ Ctx,
                                               unsigned short* __restrict__ slab1,
                                               unsigned short* __restrict__ slab2,
                                               unsigned short* __restrict__ slab3,
                                               float* __restrict__ lbase) {
  __shared__ unsigned short kbuf[64 * 64];        // [kv][d], swizzled chunks
  __shared__ unsigned short vbuf[64 * 64];        // [d][kv], swizzled chunks
  __shared__ unsigned short pbuf[4 * 2 * 16 * 72];

  int bid = blockIdx.x;
  int h = bid & 15, slot = bid >> 4;
  int g, c, nst;
  if (slot < 24)      { g = 24 + slot / 3;        c = slot % 3;        nst = 16; }
  else if (slot < 40) { g = 16 + (slot - 24) / 2; c = (slot - 24) & 1; nst = 16; }
  else if (slot < 48) { g = 8 + (slot - 40);      c = 0;               nst = 16; }
  else {
    int t2 = slot - 48;
    int mm = 7 - (t2 >> 2);
    g = mm + 8 * (t2 & 3);
    c = g >> 3;
    nst = (2 * g + 2) - 16 * c;
  }
  bool single = (g < 8);

  int t = threadIdx.x, w = t >> 6, lane = t & 63;
  int col = lane & 15, quad = lane >> 4;
  int q0a = g * 128 + w * 32;
  int q0b = q0a + 16;

  const unsigned short* Qh = Q + (size_t)h * S * HD;
  const unsigned short* Kh = K + (size_t)h * S * HD;
  const unsigned short* Vh = Vt + (size_t)h * HD * S;
  unsigned short* pla = pbuf + w * (2 * 16 * 72);
  unsigned short* plb = pla + 16 * 72;

  // Q^T B-fragments for both q-tiles
  bf8 qa0 = *(const bf8*)(Qh + (q0a + col) * HD + quad * 8);
  bf8 qa1 = *(const bf8*)(Qh + (q0a + col) * HD + 32 + quad * 8);
  bf8 qb0 = *(const bf8*)(Qh + (q0b + col) * HD + quad * 8);
  bf8 qb1 = *(const bf8*)(Qh + (q0b + col) * HD + 32 + quad * 8);

  f4 oa[4], ob[4];
#pragma unroll
  for (int dt = 0; dt < 4; dt++) { oa[dt] = (f4){0.f,0.f,0.f,0.f}; ob[dt] = (f4){0.f,0.f,0.f,0.f}; }
  float lsa = 0.f, lsb = 0.f;

  int srow = lane >> 3, sphys = lane & 7;
  int sw = col & 7;

  for (int s_ = 0; s_ < nst; s_++) {
    int kv0 = (c * 16 + s_) * 64;
    __syncthreads();             // WAR: prev-step k/v consumers done
#pragma unroll
    for (int p = 0; p < 2; p++) {
      int j = 2 * w + p;
      int row = j * 8 + srow;                  // 0..63
      int lch = sphys ^ (row & 7);
      gld_lds(Kh + (size_t)(kv0 + row) * HD + lch * 8, kbuf + j * 512);
      gld_lds(Vh + (size_t)row * S + kv0 + lch * 8, vbuf + j * 512);
    }
    __syncthreads();             // staged data visible

    // ---- scores S^T[kv][q] for both q-tiles (K-frags transient) ----
    f4 sta[4], stb[4];
#pragma unroll
    for (int tt = 0; tt < 4; tt++) {
      int kr = tt * 16 + col;
      bf8 k0 = *(const bf8*)(kbuf + kr * 64 + (quad ^ sw) * 8);
      bf8 k1 = *(const bf8*)(kbuf + kr * 64 + ((quad + 4) ^ sw) * 8);
      f4 z = {0.f, 0.f, 0.f, 0.f};
      z = MFMA(k0, qa0, z, 0, 0, 0);
      z = MFMA(k1, qa1, z, 0, 0, 0);
      sta[tt] = z;
      f4 y = {0.f, 0.f, 0.f, 0.f};
      y = MFMA(k0, qb0, y, 0, 0, 0);
      y = MFMA(k1, qb1, y, 0, 0, 0);
      stb[tt] = y;
    }

    if (kv0 + 63 > q0a) {
      int q = q0a + col;
#pragma unroll
      for (int tt = 0; tt < 4; tt++)
#pragma unroll
        for (int rr = 0; rr < 4; rr++) {
          int kv = kv0 + tt * 16 + quad * 4 + rr;
          sta[tt][rr] = (kv <= q) ? sta[tt][rr] : -1e30f;
        }
    }
    if (kv0 + 63 > q0b) {
      int q = q0b + col;
#pragma unroll
      for (int tt = 0; tt < 4; tt++)
#pragma unroll
        for (int rr = 0; rr < 4; rr++) {
          int kv = kv0 + tt * 16 + quad * 4 + rr;
          stb[tt][rr] = (kv <= q) ? stb[tt][rr] : -1e30f;
        }
    }

    // ---- fixed-max softmax: p = exp2(st); per-lane l accumulate ----
#pragma unroll
    for (int tt = 0; tt < 4; tt++) {
      float a0 = __builtin_amdgcn_exp2f(sta[tt][0]);
      float a1 = __builtin_amdgcn_exp2f(sta[tt][1]);
      float a2 = __builtin_amdgcn_exp2f(sta[tt][2]);
      float a3 = __builtin_amdgcn_exp2f(sta[tt][3]);
      lsa += (a0 + a1) + (a2 + a3);
      s4 pk;
      pk.x = (short)f2b(a0); pk.y = (short)f2b(a1);
      pk.z = (short)f2b(a2); pk.w = (short)f2b(a3);
      *(s4*)((char*)pla + col * 144 + tt * 32 + quad * 8) = pk;

      float b0 = __builtin_amdgcn_exp2f(stb[tt][0]);
      float b1 = __builtin_amdgcn_exp2f(stb[tt][1]);
      float b2 = __builtin_amdgcn_exp2f(stb[tt][2]);
      float b3 = __builtin_amdgcn_exp2f(stb[tt][3]);
      lsb += (b0 + b1) + (b2 + b3);
      s4 qk;
      qk.x = (short)f2b(b0); qk.y = (short)f2b(b1);
      qk.z = (short)f2b(b2); qk.w = (short)f2b(b3);
      *(s4*)((char*)plb + col * 144 + tt * 32 + quad * 8) = qk;
    }

    // P A-fragments (own-wave LDS; same-wave RAW ordered at the DS unit)
    bf8 pa0 = *(const bf8*)(pla + col * 72 + quad * 8);
    bf8 pa1 = *(const bf8*)(pla + col * 72 + 32 + quad * 8);
    bf8 pb0 = *(const bf8*)(plb + col * 72 + quad * 8);
    bf8 pb1 = *(const bf8*)(plb + col * 72 + 32 + quad * 8);

#pragma unroll
    for (int dt = 0; dt < 4; dt++) {
      int vr = dt * 16 + col;
      bf8 v0 = *(const bf8*)(vbuf + vr * 64 + (quad ^ sw) * 8);
      bf8 v1 = *(const bf8*)(vbuf + vr * 64 + ((quad + 4) ^ sw) * 8);
      oa[dt] = MFMA(pa0, v0, oa[dt], 0, 0, 0);
      oa[dt] = MFMA(pa1, v1, oa[dt], 0, 0, 0);
      ob[dt] = MFMA(pb0, v0, ob[dt], 0, 0, 0);
      ob[dt] = MFMA(pb1, v1, ob[dt], 0, 0, 0);
    }
  }

  // ---- epilogue ----
  lsa += __shfl_xor(lsa, 16); lsa += __shfl_xor(lsa, 32);
  lsb += __shfl_xor(lsb, 16); lsb += __shfl_xor(lsb, 32);

  if (single) {
    float ia = 1.0f / lsa, ib = 1.0f / lsb;
    float ira[4], irb[4];
#pragma unroll
    for (int r = 0; r < 4; r++) { ira[r] = __shfl(ia, quad * 4 + r); irb[r] = __shfl(ib, quad * 4 + r); }
#pragma unroll
    for (int dt = 0; dt < 4; dt++)
#pragma unroll
      for (int r = 0; r < 4; r++) {
        Ctx[(size_t)(q0a + quad * 4 + r) * DM + h * HD + dt * 16 + col] = f2b(oa[dt][r]);
        Ctx[(size_t)(q0a + quad * 4 + r) * DM + h * HD + dt * 16 + col] = f2b(oa[dt][r] * ira[r]);
        Ctx[(size_t)(q0b + quad * 4 + r) * DM + h * HD + dt * 16 + col] = f2b(ob[dt][r] * irb[r]);
      }
  } else {
    unsigned short* dst;
    int rb;
    if (c == 0)      { dst = Ctx;   rb = 0; }
    else if (c == 1) { dst = slab1; rb = 1024; }
    else if (c == 2) { dst = slab2; rb = 2048; }
    else             { dst = slab3; rb = 3072; }
    float* lg = lbase + c * (NH * S) + h * S;
    if (quad == 0) {
      lg[q0a + col] = lsa;
      lg[q0b + col] = lsb;
    }
#pragma unroll
    for (int dt = 0; dt < 4; dt++)
#pragma unroll
      for (int r = 0; r < 4; r++) {
        dst[(size_t)(q0a + quad * 4 + r - rb) * DM + h * HD + dt * 16 + col] = f2b(oa[dt][r]);
        dst[(size_t)(q0b + quad * 4 + r - rb) * DM + h * HD + dt * 16 + col] = f2b(ob[dt][r]);
      }
  }
}

// ------------- combine bf16 partials -> normalized ctx rows 1024+ -------------
__global__ void combine(unsigned short* __restrict__ Ctx,
                        const unsigned short* __restrict__ slab1,
                        const unsigned short* __restrict__ slab2,
                        const unsigned short* __restrict__ slab3,
                        const float* __restrict__ lbase) {
  int idx = blockIdx.x * 1024 + threadIdx.x * 4;   // over 3072*1024
  int r1 = idx >> 10;                               // row - 1024 (0..3071)
  int row = 1024 + r1;
  int cc = idx & 1023, h = cc >> 6;

  s4 a = *(const s4*)(Ctx + (size_t)row * DM + cc);
  s4 b = *(const s4*)(slab1 + idx);
  float v0 = b2f((unsigned short)a.x) + b2f((unsigned short)b.x);
  float v1 = b2f((unsigned short)a.y) + b2f((unsigned short)b.y);
  float v2 = b2f((unsigned short)a.z) + b2f((unsigned short)b.z);
  float v3 = b2f((unsigned short)a.w) + b2f((unsigned short)b.w);
  float l = lbase[0 * (NH * S) + h * S + row] + lbase[1 * (NH * S) + h * S + row];
  if (row >= 2048) {
    s4 d = *(const s4*)(slab2 + idx - 1024 * DM);
    v0 += b2f((unsigned short)d.x); v1 += b2f((unsigned short)d.y);
    v2 += b2f((unsigned short)d.z); v3 += b2f((unsigned short)d.w);
    l += lbase[2 * (NH * S) + h * S + row];
  }
  if (row >= 3072) {
    s4 e = *(const s4*)(slab3 + idx - 2048 * DM);
    v0 += b2f((unsigned short)e.x); v1 += b2f((unsigned short)e.y);
    v2 += b2f((unsigned short)e.z); v3 += b2f((unsigned short)e.w);
    l += lbase[3 * (NH * S) + h * S + row];
  }
  float inv = 1.0f / l;
  s4 o;
  o.x = (short)f2b(v0 * inv); o.y = (short)f2b(v1 * inv);
  o.z = (short)f2b(v2 * inv); o.w = (short)f2b(v3 * inv);
  *(s4*)(Ctx + (size_t)row * DM + cc) = o;
}

extern "C" void kernel_launch(void* const* d_in, const int* in_sizes, int n_in,
                              void* d_out, int out_size, void* d_ws, size_t ws_size,
                              hipStream_t stream) {
  const float* x     = (const float*)d_in[0];
  const float* w_qkv = (const float*)d_in[1];
  const float* b_qkv = (const float*)d_in[2];
  const float* w_out = (const float*)d_in[3];
  const float* b_out = (const float*)d_in[4];
  float* out = (float*)d_out;

  char* ws = (char*)d_ws;
  unsigned short* xb    = (unsigned short*)(ws);                        //  8 MB (dead after gemm_qkv)
  unsigned short* wqkvT = (unsigned short*)(ws + (size_t)8  * 1048576); //  6 MB (dead after gemm_qkv)
  unsigned short* woutT = (unsigned short*)(ws + (size_t)14 * 1048576); //  2 MB (live till gemm_out)
  unsigned short* Qb    = (unsigned short*)(ws + (size_t)16 * 1048576); //  8 MB
  unsigned short* Kb    = (unsigned short*)(ws + (size_t)24 * 1048576); //  8 MB
  unsigned short* Vtb   = (unsigned short*)(ws + (size_t)32 * 1048576); //  8 MB
  unsigned short* ctx   = (unsigned short*)(ws + (size_t)40 * 1048576); //  8 MB

  // dead-region reuse after gemm_qkv (13 MiB < 14 MiB):
  unsigned short* slab1 = (unsigned short*)(ws);                        // 6 MiB (rows 1024+)
  unsigned short* slab2 = (unsigned short*)(ws + (size_t)6  * 1048576); // 4 MiB (rows 2048+)
  unsigned short* slab3 = (unsigned short*)(ws + (size_t)10 * 1048576); // 2 MiB (rows 3072+)
  float*          lbase = (float*)(ws + (size_t)12 * 1048576);          // 4 x 16 x 4096 fp32 = 1 MiB

  cast_bf16<<<4096, 256, 0, stream>>>(x, xb, S * DM);
  transpose_cast<<<dim3(3 * DM / 64, DM / 64), 256, 0, stream>>>(w_qkv, wqkvT, DM, 3 * DM);
  transpose_cast<<<dim3(DM / 64, DM / 64), 256, 0, stream>>>(w_out, woutT, DM, DM);
  gemm_qkv<<<32 * 24, 256, 0, stream>>>(xb, wqkvT, b_qkv, Qb, Kb, Vtb);
  attn<<<NH * 80, 256, 0, stream>>>(Qb, Kb, Vtb, ctx, slab1, slab2, slab3, lbase);
  combine<<<3072, 256, 0, stream>>>(ctx, slab1, slab2, slab3, lbase);
  gemm_out<<<32 * 8, 256, 0, stream>>>(ctx, woutT, b_out, out);
}